// Round 8
// baseline (143.539 us; speedup 1.0000x reference)
//
#include <hip/hip_runtime.h>

#define N_ATOMS 50000
#define KMAX 32
#define EMB_ATOM 256
#define EP_IN 64
#define EP_OUT 64
#define EMB_RBF 16
#define NEDGES (N_ATOMS * KMAX)

typedef _Float16 half_t;
typedef __attribute__((ext_vector_type(2))) _Float16 half2_t;
typedef __attribute__((ext_vector_type(4))) _Float16 half4_t;
typedef __attribute__((ext_vector_type(8))) _Float16 half8_t;
typedef __attribute__((ext_vector_type(4))) float f32x4;

#define NT 3125          // 50000 / 16 atom-tiles (exact)
#define GRIDN 512        // 2 blocks/CU persistent

#define GLOAD_LDS16(g, l)                                                     \
    __builtin_amdgcn_global_load_lds(                                         \
        (const __attribute__((address_space(1))) void*)(g),                   \
        (__attribute__((address_space(3))) void*)(l), 16, 0, 0)

// grid partition of prep_all
#define XB_NB 782                       // ceil(50000/64)
#define SC_NB (NEDGES / 256)            // 6250
#define WB_NB 256
#define WU_NB 64
#define PREP_NB (XB_NB + SC_NB + WB_NB + WU_NB + 1)

// ---------------------------------------------------------------------------
// prep_all: one launch for everything before `fused`. (unchanged)
// ---------------------------------------------------------------------------
__global__ __launch_bounds__(256) void prep_all(const float* __restrict__ h,
                                                const float* __restrict__ Wd,
                                                const int*   __restrict__ ei,
                                                const int*   __restrict__ tni,
                                                const float* __restrict__ Wb,
                                                const float* __restrict__ Wu,
                                                half_t* __restrict__ xbh,
                                                int*    __restrict__ sidx,
                                                half_t* __restrict__ Wb2,
                                                half_t* __restrict__ Wu2,
                                                half_t* __restrict__ zrow) {
    __shared__ float As[16 * 68];
    __shared__ float Bs[16 * 64];
    const int bid = blockIdx.x;
    const int t = threadIdx.x;

    if (bid < XB_NB) {
        const int r0 = bid * 64;
        const int tr = t >> 4, tc = t & 15;
        float acc[4][4] = {};
        for (int k0 = 0; k0 < 256; k0 += 16) {
            {
                int m = t >> 2, kk0 = (t & 3) << 2;
                int row = r0 + m;
                float4 v = make_float4(0.f, 0.f, 0.f, 0.f);
                if (row < N_ATOMS)
                    v = *reinterpret_cast<const float4*>(&h[(size_t)row * 256 + k0 + kk0]);
                As[(kk0 + 0) * 68 + m] = v.x;
                As[(kk0 + 1) * 68 + m] = v.y;
                As[(kk0 + 2) * 68 + m] = v.z;
                As[(kk0 + 3) * 68 + m] = v.w;
            }
            {
                int kk = t >> 4, n0 = (t & 15) << 2;
                *reinterpret_cast<float4*>(&Bs[kk * 64 + n0]) =
                    *reinterpret_cast<const float4*>(&Wd[(k0 + kk) * 64 + n0]);
            }
            __syncthreads();
            #pragma unroll
            for (int kk = 0; kk < 16; ++kk) {
                float4 av = *reinterpret_cast<const float4*>(&As[kk * 68 + tr * 4]);
                float4 bv = *reinterpret_cast<const float4*>(&Bs[kk * 64 + tc * 4]);
                float aa[4] = {av.x, av.y, av.z, av.w};
                float bb[4] = {bv.x, bv.y, bv.z, bv.w};
                #pragma unroll
                for (int i = 0; i < 4; ++i)
                    #pragma unroll
                    for (int j = 0; j < 4; ++j) acc[i][j] += aa[i] * bb[j];
            }
            __syncthreads();
        }
        #pragma unroll
        for (int i = 0; i < 4; ++i) {
            int row = r0 + tr * 4 + i;
            if (row < N_ATOMS) {
                half4_t hv;
                #pragma unroll
                for (int j = 0; j < 4; ++j) hv[j] = (half_t)acc[i][j];
                *reinterpret_cast<half4_t*>(&xbh[(size_t)row * 64 + tc * 4]) = hv;
            }
        }
    } else if (bid < XB_NB + SC_NB) {
        int i = (bid - XB_NB) * 256 + t;
        int s = ei[i];
        int d = ei[NEDGES + i];
        int k = tni[i];
        sidx[d * KMAX + k] = s;
    } else if (bid < XB_NB + SC_NB + WB_NB) {
        int i = (bid - XB_NB - SC_NB) * 256 + t;
        int e = i & 7, lv = (i >> 3) & 63;
        int c = lv & 15, g = lv >> 4;
        int kh = (i >> 13) & 1, ot = i >> 14;
        int o = ot * 16 + c;
        int idx = kh * 512 + ((i >> 9) & 15) * 32 + g * 8 + e;
        int r = ((idx >> 6) & 3) * 4 + (idx & 3);
        int p = (idx >> 8) * 16 + ((idx >> 2) & 15);
        Wb2[i] = (half_t)Wb[(size_t)(r * 64 + p) * 64 + o];
    } else if (bid < XB_NB + SC_NB + WB_NB + WU_NB) {
        int i = (bid - XB_NB - SC_NB - WB_NB) * 256 + t;
        int e = i & 7, lv = (i >> 3) & 63;
        int c = lv & 15, g = lv >> 4;
        int kk = (i >> 9) & 1, nt = (i >> 10) & 1, w = i >> 11;
        int oc = w * 32 + nt * 16 + c;
        int o = kk * 32 + g * 8 + e;
        Wu2[i] = (half_t)Wu[(size_t)o * 256 + oc];
    } else {
        if (t < 128) zrow[t] = (half_t)0.f;
    }
}

// ---------------------------------------------------------------------------
// consume one staged kc-batch (16 gathered rows) at LDS byte pointer stb
// ---------------------------------------------------------------------------
__device__ __forceinline__ void consume_batch(const char* stb, int c, int g,
                                              half4_t radf, half4_t ident,
                                              f32x4 (&acc)[4]) {
    const f32x4 fzero = {0.f, 0.f, 0.f, 0.f};
    #pragma unroll
    for (int pc = 0; pc < 4; ++pc) {
        int slot = (pc * 2 + (g >> 1)) ^ (c & 7);
        half4_t gf = *reinterpret_cast<const half4_t*>(
            stb + c * 128 + slot * 16 + (g & 1) * 8);
        // layout-convert A-frag -> B-frag via identity mfma (exact)
        f32x4 tD = __builtin_amdgcn_mfma_f32_16x16x16f16(gf, ident, fzero, 0, 0, 0);
        half4_t b2;
        #pragma unroll
        for (int j = 0; j < 4; ++j) b2[j] = (half_t)tD[j];
        acc[pc] = __builtin_amdgcn_mfma_f32_16x16x16f16(radf, b2, acc[pc], 0, 0, 0);
    }
}

// issue one kc-batch (2 x global_load_lds, 1 KB each): sidx from svv via shfl,
// staged into byte pointer (bp + bofs)
#define ISSUEX(svv, bp, as_, kc_, bofs) do {                                  \
    _Pragma("unroll")                                                         \
    for (int h_ = 0; h_ < 2; ++h_) {                                          \
        int s_ = __shfl(svv, (as_) * 32 + (kc_) * 16 + h_ * 8 + (l >> 3), 64);\
        const half_t* src_ = ((unsigned)s_ < (unsigned)N_ATOMS)               \
            ? (xbh + (size_t)s_ * 64) : zrow;                                 \
        src_ += (((l & 7) ^ (l >> 3)) << 3);  /* swizzled 16B chunk */        \
        GLOAD_LDS16(src_, (half_t*)((bp) + (bofs)) + h_ * 512);               \
    }                                                                         \
} while (0)

#define WRITE_ATOMX(bp, a_, accv) do {                                        \
    _Pragma("unroll")                                                         \
    for (int pc = 0; pc < 4; ++pc) {                                          \
        half4_t hv;                                                           \
        _Pragma("unroll")                                                     \
        for (int j = 0; j < 4; ++j) hv[j] = (half_t)accv[pc][j];              \
        int byte_ = ((a_) * 2048 + pc * 512 + g * 128 + c * 8) ^              \
                    (((a_) & 7) << 4);                                        \
        *reinterpret_cast<half4_t*>((bp) + byte_) = hv;                       \
    }                                                                         \
} while (0)

#define WAIT_VM(n) do {                                                       \
    asm volatile("s_waitcnt vmcnt(" #n ")" ::: "memory");                     \
    __builtin_amdgcn_sched_barrier(0);                                        \
} while (0)

#define WAIT_LGKM() do {                                                      \
    asm volatile("s_waitcnt lgkmcnt(0)" ::: "memory");                        \
    __builtin_amdgcn_sched_barrier(0);                                        \
} while (0)

#define SBAR() __builtin_amdgcn_sched_barrier(0)

// ---------------------------------------------------------------------------
// Fused steps 3-5, persistent. 512 blocks x 512 threads; each block loops
// over tiles of 16 atoms (tile = bid, bid+512, ...). Ping-pong xba2s buffers:
// tile i+1's sidx (top of body) + rad + first-atom gathers (end of phase 1,
// into buffer p^1) fly under phases 2/3 of tile i. Wu2 loop-resident in regs.
// Uniform vmcnt chain 1/2/0 (old stores over-drained for free).
// ---------------------------------------------------------------------------
__global__ __launch_bounds__(512, 4) void fused(const half_t* __restrict__ xbh,
                                                const float*  __restrict__ rad,   // (N,16,32) f32
                                                const int*    __restrict__ sidxg, // (N,32)
                                                const half_t* __restrict__ Wb2,   // (65536) permuted
                                                const half_t* __restrict__ Wu2,   // (16384) permuted
                                                const half_t* __restrict__ zrow,  // 128 zero f16
                                                float* __restrict__ out) {        // (N,256)
    __shared__ __align__(16) half_t xba2s[2][16 * 1024]; // 64 KB ping-pong
    __shared__ __align__(16) float  preds[2 * 16 * 68];  // 8704 B split-K partials
    __shared__ __align__(16) half_t houts[16 * 64];      // 2048 B, row-swizzled

    const int t = threadIdx.x;
    const int w = t >> 6;        // wave 0..7
    const int l = t & 63;
    const int c = l & 15;
    const int g = l >> 4;
    const int ot = w >> 1, kh = w & 1;

    const f32x4 fzero = {0.f, 0.f, 0.f, 0.f};

    half4_t ident;  // identity B-frag: B[k][n] = (k==n)
    #pragma unroll
    for (int j = 0; j < 4; ++j) ident[j] = (half_t)((g * 4 + j == c) ? 1.0f : 0.0f);

    // loop-resident Wu2 fragments (16 VGPR)
    half8_t wuf[2][2];
    #pragma unroll
    for (int nt = 0; nt < 2; ++nt)
        #pragma unroll
        for (int kk = 0; kk < 2; ++kk)
            wuf[nt][kk] = *reinterpret_cast<const half8_t*>(
                &Wu2[(size_t)(((w * 2 + nt) * 2 + kk) * 64 + l) * 8]);

    const half_t* wbbase = &Wb2[(size_t)((ot * 2 + kh) * 16) * 512];

    int tile = blockIdx.x;
    int p = 0;

    // ---- preamble: prologue for the first tile into buffer 0 ----
    int sv = sidxg[(size_t)(tile * 16 + w * 2) * KMAX + l];
    f32x4 rv[4];
    #pragma unroll
    for (int q = 0; q < 4; ++q)
        rv[q] = *reinterpret_cast<const f32x4*>(
            rad + (size_t)(tile * 16 + w * 2) * 512 + q * 256 + l * 4);
    {
        char* Rb0 = reinterpret_cast<char*>(&xba2s[0][0]) + w * 4096;
        ISSUEX(sv, Rb0, 0, 0, 0);
        ISSUEX(sv, Rb0, 0, 1, 2048);
    }
    SBAR();

    while (tile < NT) {
        char* Xp = reinterpret_cast<char*>(&xba2s[p][0]);
        char* Rb = Xp + w * 4096;
        const int a0 = tile * 16;

        // radF from rv (shfl-both-then-select; compiler waits rv, leaves
        // gathers in flight): radF[as][kc][j] = rad[atom as][r=c][kc*16+g*4+j]
        half4_t radF[2][2];
        #pragma unroll
        for (int as = 0; as < 2; ++as)
            #pragma unroll
            for (int kc = 0; kc < 2; ++kc) {
                int srcl = (c & 7) * 8 + kc * 4 + g;
                #pragma unroll
                for (int j = 0; j < 4; ++j) {
                    float lo = __shfl(rv[as * 2 + 0][j], srcl, 64);
                    float hi = __shfl(rv[as * 2 + 1][j], srcl, 64);
                    radF[as][kc][j] = (half_t)((c & 8) ? hi : lo);
                }
            }

        // issue next tile's sidx EARLY (retired well before its shfl use)
        int tn = tile + GRIDN;
        int tnc = (tn < NT) ? tn : tile;   // clamp: dummy reload on last tile
        int sv_next = sidxg[(size_t)(tnc * 16 + w * 2) * KMAX + l];
        SBAR();

        f32x4 acc0[4] = {fzero, fzero, fzero, fzero};
        f32x4 acc1[4] = {fzero, fzero, fzero, fzero};

        // ---- phase-1 chain; counts uniform (old stores drain for free) ----
        WAIT_VM(1);                                  // A0k0+A0k1 landed
        consume_batch(Rb, c, g, radF[0][0], ident, acc0);
        WAIT_LGKM(); ISSUEX(sv, Rb, 1, 0, 0);        // A1k0 -> Rb+0
        consume_batch(Rb + 2048, c, g, radF[0][1], ident, acc0);
        WAIT_LGKM(); ISSUEX(sv, Rb, 1, 1, 2048);     // A1k1 -> Rb+2048
        WAIT_VM(2);                                  // A1k0 landed
        consume_batch(Rb, c, g, radF[1][0], ident, acc1);
        WRITE_ATOMX(Xp, w * 2, acc0);
        WAIT_VM(0);                                  // A1k1 landed
        consume_batch(Rb + 2048, c, g, radF[1][1], ident, acc1);
        WRITE_ATOMX(Xp, w * 2 + 1, acc1);

        // ---- next-tile prologue: rad + first-atom gathers into buffer p^1 --
        if (tn < NT) {
            #pragma unroll
            for (int q = 0; q < 4; ++q)
                rv[q] = *reinterpret_cast<const f32x4*>(
                    rad + (size_t)(tn * 16 + w * 2) * 512 + q * 256 + l * 4);
            char* Rn = reinterpret_cast<char*>(&xba2s[p ^ 1][0]) + w * 4096;
            ISSUEX(sv_next, Rn, 0, 0, 0);
            ISSUEX(sv_next, Rn, 0, 1, 2048);
        }
        sv = sv_next;
        SBAR();

        // this tile's Wb2 fragments (L2-hot), fly across the barrier
        half8_t bfr[8];
        #pragma unroll
        for (int j = 0; j < 8; ++j)
            bfr[j] = *reinterpret_cast<const half8_t*>(wbbase + j * 512 + l * 8);
        SBAR();

        __syncthreads();   // bar1: phase-1 writes visible

        // ---- phase 2: h_out(16x64) = xba2(16x1024) @ Wb, split-K ----------
        {
            f32x4 acc2[4] = {fzero, fzero, fzero, fzero};
            #pragma unroll
            for (int j = 0; j < 16; ++j) {
                int abyte = (c * 2048 + (kh * 512 + j * 32) * 2 + g * 16) ^ ((c & 7) << 4);
                half8_t af = *reinterpret_cast<const half8_t*>(Xp + abyte);
                acc2[j & 3] = __builtin_amdgcn_mfma_f32_16x16x32_f16(af, bfr[j & 7], acc2[j & 3], 0, 0, 0);
                if (j < 8)
                    bfr[j & 7] = *reinterpret_cast<const half8_t*>(wbbase + (j + 8) * 512 + l * 8);
            }
            f32x4 accT = acc2[0] + acc2[1] + acc2[2] + acc2[3];
            #pragma unroll
            for (int i = 0; i < 4; ++i)
                preds[kh * 1088 + (g * 4 + i) * 68 + ot * 16 + c] = accT[i];
        }
        __syncthreads();   // bar2

        // reduce split-K partials -> houts f16 (row-swizzled)
        {
            int m = t >> 5, oj = (t & 31) << 1;
            float s0 = preds[m * 68 + oj]     + preds[1088 + m * 68 + oj];
            float s1 = preds[m * 68 + oj + 1] + preds[1088 + m * 68 + oj + 1];
            half2_t hv; hv[0] = (half_t)s0; hv[1] = (half_t)s1;
            int byte_ = (m * 128 + oj * 2) ^ ((m & 7) << 4);
            *reinterpret_cast<half2_t*>(reinterpret_cast<char*>(houts) + byte_) = hv;
        }
        __syncthreads();   // bar3

        // ---- phase 3: out(16x256) = hout(16x64) @ Wu (Wu in regs) ---------
        {
            half8_t ha[2];
            #pragma unroll
            for (int kk = 0; kk < 2; ++kk) {
                int byte_ = (c * 128 + kk * 64 + g * 16) ^ ((c & 7) << 4);
                ha[kk] = *reinterpret_cast<const half8_t*>(
                    reinterpret_cast<const char*>(houts) + byte_);
            }
            #pragma unroll
            for (int nt = 0; nt < 2; ++nt) {
                int oc0 = w * 32 + nt * 16;
                f32x4 acc3 = fzero;
                acc3 = __builtin_amdgcn_mfma_f32_16x16x32_f16(ha[0], wuf[nt][0], acc3, 0, 0, 0);
                acc3 = __builtin_amdgcn_mfma_f32_16x16x32_f16(ha[1], wuf[nt][1], acc3, 0, 0, 0);
                #pragma unroll
                for (int i = 0; i < 4; ++i)
                    out[(size_t)(a0 + g * 4 + i) * 256 + oc0 + c] = acc3[i];
            }
        }

        tile += GRIDN;
        p ^= 1;
    }
}

// ---------------------------------------------------------------------------
extern "C" void kernel_launch(void* const* d_in, const int* in_sizes, int n_in,
                              void* d_out, int out_size, void* d_ws, size_t ws_size,
                              hipStream_t stream) {
    const float* h   = (const float*)d_in[0];
    const float* rad = (const float*)d_in[1];
    const int*   ei  = (const int*)d_in[2];
    const int*   tni = (const int*)d_in[3];
    const float* Wd  = (const float*)d_in[4];
    const float* Wb  = (const float*)d_in[5];
    const float* Wu  = (const float*)d_in[6];
    float* out = (float*)d_out;

    // workspace: xbh f16 6.4MB | sidx i32 6.4MB | Wb2 128KB | Wu2 32KB | zrow 256B
    half_t* xbh  = (half_t*)d_ws;
    int*    sidx = (int*)((char*)d_ws + (size_t)N_ATOMS * EP_IN * sizeof(half_t));
    half_t* Wb2  = (half_t*)((char*)sidx + (size_t)NEDGES * sizeof(int));
    half_t* Wu2  = Wb2 + 64 * 1024;
    half_t* zrow = Wu2 + 16384;

    prep_all<<<PREP_NB, 256, 0, stream>>>(h, Wd, ei, tni, Wb, Wu,
                                          xbh, sidx, Wb2, Wu2, zrow);
    fused<<<GRIDN, 512, 0, stream>>>(xbh, rad, sidx, Wb2, Wu2, zrow, out);
}

// Round 9
// 74.544 us; speedup vs baseline: 1.9255x; 1.9255x over previous
//
#include <hip/hip_runtime.h>

#define N_ATOMS 50000
#define KMAX 32
#define EMB_ATOM 256
#define EP_IN 64
#define EP_OUT 64
#define EMB_RBF 16
#define NEDGES (N_ATOMS * KMAX)

typedef _Float16 half_t;
typedef __attribute__((ext_vector_type(2))) _Float16 half2_t;
typedef __attribute__((ext_vector_type(4))) _Float16 half4_t;
typedef __attribute__((ext_vector_type(8))) _Float16 half8_t;
typedef __attribute__((ext_vector_type(4))) float f32x4;

static_assert(N_ATOMS % 16 == 0, "fused kernel assumes 16 atoms per block");

#define GLOAD_LDS16(g, l)                                                     \
    __builtin_amdgcn_global_load_lds(                                         \
        (const __attribute__((address_space(1))) void*)(g),                   \
        (__attribute__((address_space(3))) void*)(l), 16, 0, 0)

// prep_w grid: Wd2 (64) | Wb2 (256) | Wu2 (64) | zrow (1)
#define PW_WD 64
#define PW_WB 256
#define PW_WU 64
#define PREP_W_NB (PW_WD + PW_WB + PW_WU + 1)

// prep_main grid: xb MFMA (782 blocks x 64 rows) | scatter (6250)
#define XB2_NB 782
#define SC_NB (NEDGES / 256)
#define PREP_MAIN_NB (XB2_NB + SC_NB)

// ---------------------------------------------------------------------------
// prep_w: weight permutations to f16 (tiny, runs first).
//  Wd2[i]: e=i&7 | l=(i>>3)&63 | s=(i>>9)&7 | nt=i>>12
//          -> B-frag linear: B[k=s*32+(l>>4)*8+e][n=nt*16+(l&15)] = Wd[k*64+n]
// ---------------------------------------------------------------------------
__global__ __launch_bounds__(256) void prep_w(const float* __restrict__ Wd,
                                              const float* __restrict__ Wb,
                                              const float* __restrict__ Wu,
                                              half_t* __restrict__ Wd2,
                                              half_t* __restrict__ Wb2,
                                              half_t* __restrict__ Wu2,
                                              half_t* __restrict__ zrow) {
    const int bid = blockIdx.x;
    const int t = threadIdx.x;
    if (bid < PW_WD) {
        int i = bid * 256 + t;  // 16384
        int e = i & 7, lv = (i >> 3) & 63, s = (i >> 9) & 7, nt = i >> 12;
        int c = lv & 15, g = lv >> 4;
        int k = s * 32 + g * 8 + e;
        int n = nt * 16 + c;
        Wd2[i] = (half_t)Wd[(size_t)k * 64 + n];
    } else if (bid < PW_WD + PW_WB) {
        int i = (bid - PW_WD) * 256 + t;  // 65536
        int e = i & 7, lv = (i >> 3) & 63;
        int c = lv & 15, g = lv >> 4;
        int kh = (i >> 13) & 1, ot = i >> 14;
        int o = ot * 16 + c;
        int idx = kh * 512 + ((i >> 9) & 15) * 32 + g * 8 + e;
        int r = ((idx >> 6) & 3) * 4 + (idx & 3);
        int p = (idx >> 8) * 16 + ((idx >> 2) & 15);
        Wb2[i] = (half_t)Wb[(size_t)(r * 64 + p) * 64 + o];
    } else if (bid < PW_WD + PW_WB + PW_WU) {
        int i = (bid - PW_WD - PW_WB) * 256 + t;  // 16384
        int e = i & 7, lv = (i >> 3) & 63;
        int c = lv & 15, g = lv >> 4;
        int kk = (i >> 9) & 1, nt = (i >> 10) & 1, w = i >> 11;
        int oc = w * 32 + nt * 16 + c;
        int o = kk * 32 + g * 8 + e;
        Wu2[i] = (half_t)Wu[(size_t)o * 256 + oc];
    } else {
        if (t < 128) zrow[t] = (half_t)0.f;
    }
}

// ---------------------------------------------------------------------------
// prep_main: xb = h @ Wd via MFMA f16 (f32 accum) + scatter sidx.
//  xb blocks: 256 threads = 4 waves, 64 rows/block (16 rows/wave).
//  Per wave: 8 K-steps x 4 n-tiles of mfma_16x16x32_f16.
//   A-frag: lane m=c=row, k=g*8+e <- h[row][k] contiguous f32x8 -> f16
//   B-frag: lane n=c, k=g*8+e <- Wd2 linear (L2-hot)
//   D: lane (c,g) holds rows g*4+i, col c.
// ---------------------------------------------------------------------------
__global__ __launch_bounds__(256) void prep_main(const float* __restrict__ h,
                                                 const int*   __restrict__ ei,
                                                 const int*   __restrict__ tni,
                                                 const half_t* __restrict__ Wd2,
                                                 half_t* __restrict__ xbh,
                                                 int*    __restrict__ sidx) {
    const int bid = blockIdx.x;
    const int t = threadIdx.x;
    if (bid < XB2_NB) {
        const int w = t >> 6, l = t & 63;
        const int c = l & 15, g = l >> 4;
        const int r0 = bid * 64 + w * 16;
        const f32x4 fzero = {0.f, 0.f, 0.f, 0.f};
        f32x4 acc[4] = {fzero, fzero, fzero, fzero};

        int row_ld = r0 + c;
        if (row_ld > N_ATOMS - 1) row_ld = N_ATOMS - 1;  // clamp tail loads
        const float* hrow = h + (size_t)row_ld * 256;

        #pragma unroll
        for (int s = 0; s < 8; ++s) {
            f32x4 h0 = *reinterpret_cast<const f32x4*>(hrow + s * 32 + g * 8);
            f32x4 h1 = *reinterpret_cast<const f32x4*>(hrow + s * 32 + g * 8 + 4);
            half8_t af;
            #pragma unroll
            for (int j = 0; j < 4; ++j) { af[j] = (half_t)h0[j]; af[4 + j] = (half_t)h1[j]; }
            #pragma unroll
            for (int nt = 0; nt < 4; ++nt) {
                half8_t bf = *reinterpret_cast<const half8_t*>(
                    &Wd2[(size_t)(nt * 8 + s) * 512 + l * 8]);
                acc[nt] = __builtin_amdgcn_mfma_f32_16x16x32_f16(af, bf, acc[nt], 0, 0, 0);
            }
        }
        #pragma unroll
        for (int nt = 0; nt < 4; ++nt)
            #pragma unroll
            for (int i = 0; i < 4; ++i) {
                int row = r0 + g * 4 + i;
                if (row < N_ATOMS)
                    xbh[(size_t)row * 64 + nt * 16 + c] = (half_t)acc[nt][i];
            }
    } else {
        int i = (bid - XB2_NB) * 256 + t;
        int s = ei[i];
        int d = ei[NEDGES + i];
        int k = tni[i];
        sidx[d * KMAX + k] = s;
    }
}

// ---------------------------------------------------------------------------
// consume one staged kc-batch (16 gathered rows) at LDS byte pointer stb
// ---------------------------------------------------------------------------
__device__ __forceinline__ void consume_batch(const char* stb, int c, int g,
                                              half4_t radf, half4_t ident,
                                              f32x4 (&acc)[4]) {
    const f32x4 fzero = {0.f, 0.f, 0.f, 0.f};
    #pragma unroll
    for (int pc = 0; pc < 4; ++pc) {
        int slot = (pc * 2 + (g >> 1)) ^ (c & 7);
        half4_t gf = *reinterpret_cast<const half4_t*>(
            stb + c * 128 + slot * 16 + (g & 1) * 8);
        // layout-convert A-frag -> B-frag via identity mfma (exact)
        f32x4 tD = __builtin_amdgcn_mfma_f32_16x16x16f16(gf, ident, fzero, 0, 0, 0);
        half4_t b2;
        #pragma unroll
        for (int j = 0; j < 4; ++j) b2[j] = (half_t)tD[j];
        acc[pc] = __builtin_amdgcn_mfma_f32_16x16x16f16(radf, b2, acc[pc], 0, 0, 0);
    }
}

// issue one kc-batch (2 x global_load_lds, 1 KB each) into Rbase+bufb
#define ISSUE(as, kc, bufb) do {                                              \
    _Pragma("unroll")                                                         \
    for (int h_ = 0; h_ < 2; ++h_) {                                          \
        int s_ = __shfl(sv, (as) * 32 + (kc) * 16 + h_ * 8 + (l >> 3), 64);   \
        const half_t* src_ = ((unsigned)s_ < (unsigned)N_ATOMS)               \
            ? (xbh + (size_t)s_ * 64) : zrow;                                 \
        src_ += (((l & 7) ^ (l >> 3)) << 3);  /* swizzled 16B chunk */        \
        GLOAD_LDS16(src_, (half_t*)(Rbase + (bufb)) + h_ * 512);              \
    }                                                                         \
} while (0)

#define WRITE_ATOM(a_, accv) do {                                             \
    _Pragma("unroll")                                                         \
    for (int pc = 0; pc < 4; ++pc) {                                          \
        half4_t hv;                                                           \
        _Pragma("unroll")                                                     \
        for (int j = 0; j < 4; ++j) hv[j] = (half_t)accv[pc][j];              \
        int byte_ = ((a_) * 2048 + pc * 512 + g * 128 + c * 8) ^              \
                    (((a_) & 7) << 4);                                        \
        *reinterpret_cast<half4_t*>(reinterpret_cast<char*>(xba2s) + byte_) = hv; \
    }                                                                         \
} while (0)

#define WAIT_VM(n) do {                                                       \
    asm volatile("s_waitcnt vmcnt(" #n ")" ::: "memory");                     \
    __builtin_amdgcn_sched_barrier(0);                                        \
} while (0)

#define WAIT_LGKM() do {                                                      \
    asm volatile("s_waitcnt lgkmcnt(0)" ::: "memory");                        \
    __builtin_amdgcn_sched_barrier(0);                                        \
} while (0)

#define SBAR() __builtin_amdgcn_sched_barrier(0)

// ---------------------------------------------------------------------------
// Fused steps 3-5 (EXACT round-6 structure: best measured, 67 us).
// 16 atoms / block, 8 waves, 512 threads; stage aliases xba2s; FIFO prologue
// sidx, rad x4, B0, B1, Wb2 x4; counted vmcnt 6/6/2/0.
// ---------------------------------------------------------------------------
__global__ __launch_bounds__(512, 6) void fused(const half_t* __restrict__ xbh,
                                                const float*  __restrict__ rad,   // (N,16,32) f32
                                                const int*    __restrict__ sidxg, // (N,32)
                                                const half_t* __restrict__ Wb2,   // (65536) permuted
                                                const half_t* __restrict__ Wu2,   // (16384) permuted
                                                const half_t* __restrict__ zrow,  // 128 zero f16
                                                float* __restrict__ out) {        // (N,256)
    __shared__ __align__(16) half_t xba2s[16 * 1024];  // 32 KB, outputs + stage (aliased)
    __shared__ __align__(16) float  preds[2 * 16 * 68]; // 8704 B split-K partials
    __shared__ __align__(16) half_t houts[16 * 64];     // 2048 B, row-swizzled

    const int t = threadIdx.x;
    const int w = t >> 6;        // wave 0..7
    const int l = t & 63;
    const int c = l & 15;
    const int g = l >> 4;
    const int a0 = blockIdx.x * 16;

    char* Rbase = reinterpret_cast<char*>(xba2s) + w * 4096;  // wave region: buf0 | buf1

    const f32x4 fzero = {0.f, 0.f, 0.f, 0.f};

    // ---- FIFO prologue: issue in consume order ----
    int sv = sidxg[(size_t)(a0 + w * 2) * KMAX + l];
    const float* radw = &rad[(size_t)(a0 + w * 2) * 512];
    f32x4 rv[4];
    #pragma unroll
    for (int q = 0; q < 4; ++q)
        rv[q] = *reinterpret_cast<const f32x4*>(radw + q * 256 + l * 4);

    ISSUE(0, 0, 0);
    ISSUE(0, 1, 2048);
    SBAR();

    const int ot = w >> 1, kh = w & 1;
    const half_t* wbbase = &Wb2[(size_t)((ot * 2 + kh) * 16) * 512];
    half8_t bfr[4];
    #pragma unroll
    for (int j = 0; j < 4; ++j)
        bfr[j] = *reinterpret_cast<const half8_t*>(wbbase + j * 512 + l * 8);
    SBAR();

    // radF via shfl-both-then-select (dest-lane predicate after the shfl)
    half4_t radF[2][2];
    #pragma unroll
    for (int as = 0; as < 2; ++as)
        #pragma unroll
        for (int kc = 0; kc < 2; ++kc) {
            int srcl = (c & 7) * 8 + kc * 4 + g;
            #pragma unroll
            for (int j = 0; j < 4; ++j) {
                float lo = __shfl(rv[as * 2 + 0][j], srcl, 64);
                float hi = __shfl(rv[as * 2 + 1][j], srcl, 64);
                radF[as][kc][j] = (half_t)((c & 8) ? hi : lo);
            }
        }

    half4_t ident;  // identity B-frag: B[k][n] = (k==n)
    #pragma unroll
    for (int j = 0; j < 4; ++j) ident[j] = (half_t)((g * 4 + j == c) ? 1.0f : 0.0f);

    f32x4 acc0[4] = {fzero, fzero, fzero, fzero};
    f32x4 acc1[4] = {fzero, fzero, fzero, fzero};

    // ---- depth-2 consume chain, counted vmcnt ----
    WAIT_VM(6);                       // sidx+rad+B0 retired; B1+Wb2 in flight
    consume_batch(Rbase, c, g, radF[0][0], ident, acc0);
    WAIT_LGKM();
    ISSUE(1, 0, 0);                   // B2 -> buf0
    WAIT_VM(6);                       // B1 retired; Wb2+B2 in flight
    consume_batch(Rbase + 2048, c, g, radF[0][1], ident, acc0);
    WAIT_LGKM();
    ISSUE(1, 1, 2048);                // B3 -> buf1
    WAIT_VM(2);                       // Wb2+B2 retired; B3 in flight
    consume_batch(Rbase, c, g, radF[1][0], ident, acc1);
    WRITE_ATOM(w * 2, acc0);          // overwrite buf0 region (B2 consumed)
    WAIT_VM(0);                       // B3 retired
    consume_batch(Rbase + 2048, c, g, radF[1][1], ident, acc1);
    WRITE_ATOM(w * 2 + 1, acc1);      // overwrite buf1 region

    __syncthreads();

    // ---------------- phase 2: h_out(16x64) = xba2(16x1024) @ Wb ------------
    {
        f32x4 acc2[4] = {fzero, fzero, fzero, fzero};
        #pragma unroll
        for (int j = 0; j < 16; ++j) {
            int abyte = (c * 2048 + (kh * 512 + j * 32) * 2 + g * 16) ^ ((c & 7) << 4);
            half8_t af = *reinterpret_cast<const half8_t*>(
                reinterpret_cast<const char*>(xba2s) + abyte);
            half8_t bf = bfr[j & 3];
            if (j + 4 < 16)
                bfr[j & 3] = *reinterpret_cast<const half8_t*>(wbbase + (j + 4) * 512 + l * 8);
            acc2[j & 3] = __builtin_amdgcn_mfma_f32_16x16x32_f16(af, bf, acc2[j & 3], 0, 0, 0);
        }
        f32x4 accT = acc2[0] + acc2[1] + acc2[2] + acc2[3];
        #pragma unroll
        for (int i = 0; i < 4; ++i)
            preds[kh * 1088 + (g * 4 + i) * 68 + ot * 16 + c] = accT[i];
    }

    // prefetch all 4 Wu2 fragments across the barrier
    half8_t wuf[2][2];
    #pragma unroll
    for (int nt = 0; nt < 2; ++nt)
        #pragma unroll
        for (int kk = 0; kk < 2; ++kk)
            wuf[nt][kk] = *reinterpret_cast<const half8_t*>(
                &Wu2[(size_t)(((w * 2 + nt) * 2 + kk) * 64 + l) * 8]);

    __syncthreads();

    // reduce split-K partials -> houts f16 (row-swizzled)
    {
        int m = t >> 5, oj = (t & 31) << 1;
        float s0 = preds[m * 68 + oj]     + preds[1088 + m * 68 + oj];
        float s1 = preds[m * 68 + oj + 1] + preds[1088 + m * 68 + oj + 1];
        half2_t hv; hv[0] = (half_t)s0; hv[1] = (half_t)s1;
        int byte_ = (m * 128 + oj * 2) ^ ((m & 7) << 4);
        *reinterpret_cast<half2_t*>(reinterpret_cast<char*>(houts) + byte_) = hv;
    }
    __syncthreads();

    // ---------------- phase 3: out(16x256) = hout(16x64) @ Wu ---------------
    half8_t ha[2];
    #pragma unroll
    for (int kk = 0; kk < 2; ++kk) {
        int byte_ = (c * 128 + kk * 64 + g * 16) ^ ((c & 7) << 4);
        ha[kk] = *reinterpret_cast<const half8_t*>(
            reinterpret_cast<const char*>(houts) + byte_);
    }
    #pragma unroll
    for (int nt = 0; nt < 2; ++nt) {
        int oc0 = w * 32 + nt * 16;
        f32x4 acc3 = fzero;
        acc3 = __builtin_amdgcn_mfma_f32_16x16x32_f16(ha[0], wuf[nt][0], acc3, 0, 0, 0);
        acc3 = __builtin_amdgcn_mfma_f32_16x16x32_f16(ha[1], wuf[nt][1], acc3, 0, 0, 0);
        #pragma unroll
        for (int i = 0; i < 4; ++i)
            out[(size_t)(a0 + g * 4 + i) * 256 + oc0 + c] = acc3[i];
    }
}

// ---------------------------------------------------------------------------
extern "C" void kernel_launch(void* const* d_in, const int* in_sizes, int n_in,
                              void* d_out, int out_size, void* d_ws, size_t ws_size,
                              hipStream_t stream) {
    const float* h   = (const float*)d_in[0];
    const float* rad = (const float*)d_in[1];
    const int*   ei  = (const int*)d_in[2];
    const int*   tni = (const int*)d_in[3];
    const float* Wd  = (const float*)d_in[4];
    const float* Wb  = (const float*)d_in[5];
    const float* Wu  = (const float*)d_in[6];
    float* out = (float*)d_out;

    // workspace: xbh f16 6.4MB | sidx i32 6.4MB | Wb2 128KB | Wu2 32KB | Wd2 32KB | zrow 256B
    half_t* xbh  = (half_t*)d_ws;
    int*    sidx = (int*)((char*)d_ws + (size_t)N_ATOMS * EP_IN * sizeof(half_t));
    half_t* Wb2  = (half_t*)((char*)sidx + (size_t)NEDGES * sizeof(int));
    half_t* Wu2  = Wb2 + 64 * 1024;
    half_t* Wd2  = Wu2 + 16384;
    half_t* zrow = Wd2 + 16384;

    prep_w<<<PREP_W_NB, 256, 0, stream>>>(Wd, Wb, Wu, Wd2, Wb2, Wu2, zrow);
    prep_main<<<PREP_MAIN_NB, 256, 0, stream>>>(h, ei, tni, Wd2, xbh, sidx);
    fused<<<N_ATOMS / 16, 512, 0, stream>>>(xbh, rad, sidx, Wb2, Wu2, zrow, out);
}